// Round 4
// baseline (3124.903 us; speedup 1.0000x reference)
//
#include <hip/hip_runtime.h>
#include <stdint.h>

#define B_ 4
#define S_ 2048
#define E_ 1024
#define H_ 16
#define D_ 64

typedef unsigned short u16;
typedef u16 u16x8 __attribute__((ext_vector_type(8)));
typedef __bf16 bf16x8 __attribute__((ext_vector_type(8)));
typedef float f32x4 __attribute__((ext_vector_type(4)));

__device__ __forceinline__ float bf2f(u16 x) {
  unsigned int v = ((unsigned int)x) << 16;
  return __builtin_bit_cast(float, v);
}
__device__ __forceinline__ u16 f2bf(float f) {
  unsigned int u = __builtin_bit_cast(unsigned int, f);
  unsigned int r = (u + 0x7fffu + ((u >> 16) & 1u)) >> 16;
  return (u16)r;
}

// ------------- batched 32x32 transpose + fp32->bf16 cast: dst[C,R] = bf16(src[R,C]^T) -------------
__global__ __launch_bounds__(256) void castT_k(const float* __restrict__ src,
                                               u16* __restrict__ dst, int R, int C) {
  long bofs = (long)blockIdx.z * R * C;
  src += bofs; dst += bofs;
  __shared__ u16 t[32][33];
  int c0 = blockIdx.x * 32, r0 = blockIdx.y * 32;
  int lc = threadIdx.x & 31, lr8 = threadIdx.x >> 5;
#pragma unroll
  for (int i = 0; i < 4; i++) {
    int lr = lr8 + i * 8;
    t[lr][lc] = f2bf(src[(long)(r0 + lr) * C + c0 + lc]);
  }
  __syncthreads();
#pragma unroll
  for (int i = 0; i < 4; i++) {
    int lr = lr8 + i * 8;
    dst[(long)(c0 + lr) * R + r0 + lc] = t[lc][lr];
  }
}

// ------------- MFMA GEMM: C[M,N] = A[M,K] @ BT[N,K]^T (+bias,+resid,relu) -------------
// A: fp32 (cast to bf16 in staging) or bf16, per AF32. C: fp32 or bf16, per CF32.
// 64x64 tile, 4 waves (2x2), each wave 32x32 via 2x2 mfma_f32_16x16x32_bf16.
template <bool AF32, bool CF32>
__global__ __launch_bounds__(256) void gemm_bt(const void* __restrict__ Av,
                                               const u16* __restrict__ BT,
                                               void* __restrict__ Cv,
                                               const float* __restrict__ bias,
                                               const float* __restrict__ resid,
                                               int M, int N, int K, int relu) {
  __shared__ u16 As[64][40];  // pad 32->40
  __shared__ u16 Bs[64][40];
  int m0 = blockIdx.y * 64, n0 = blockIdx.x * 64;
  int tid = threadIdx.x;
  int wave = tid >> 6, lane = tid & 63;
  int wm = wave >> 1, wn = wave & 1;
  int srow = tid >> 2, scol = (tid & 3) * 8;
  const u16* Bp = BT + (long)(n0 + srow) * K + scol;

  f32x4 acc[2][2] = {};

  int kf = (lane >> 4) * 8;
  int fr = lane & 15;

  for (int k0 = 0; k0 < K; k0 += 32) {
    __syncthreads();
    if (AF32) {
      const float* Ap = (const float*)Av + (long)(m0 + srow) * K + scol + k0;
      f32x4 f0 = *(const f32x4*)Ap;
      f32x4 f1 = *(const f32x4*)(Ap + 4);
      u16x8 t;
#pragma unroll
      for (int j = 0; j < 4; j++) { t[j] = f2bf(f0[j]); t[j + 4] = f2bf(f1[j]); }
      *(u16x8*)(&As[srow][scol]) = t;
    } else {
      const u16* Ap = (const u16*)Av + (long)(m0 + srow) * K + scol + k0;
      *(u16x8*)(&As[srow][scol]) = *(const u16x8*)Ap;
    }
    *(u16x8*)(&Bs[srow][scol]) = *(const u16x8*)(Bp + k0);
    __syncthreads();
    bf16x8 a0 = __builtin_bit_cast(bf16x8, *(const u16x8*)&As[wm * 32 + fr][kf]);
    bf16x8 a1 = __builtin_bit_cast(bf16x8, *(const u16x8*)&As[wm * 32 + 16 + fr][kf]);
    bf16x8 b0 = __builtin_bit_cast(bf16x8, *(const u16x8*)&Bs[wn * 32 + fr][kf]);
    bf16x8 b1 = __builtin_bit_cast(bf16x8, *(const u16x8*)&Bs[wn * 32 + 16 + fr][kf]);
    acc[0][0] = __builtin_amdgcn_mfma_f32_16x16x32_bf16(a0, b0, acc[0][0], 0, 0, 0);
    acc[0][1] = __builtin_amdgcn_mfma_f32_16x16x32_bf16(a0, b1, acc[0][1], 0, 0, 0);
    acc[1][0] = __builtin_amdgcn_mfma_f32_16x16x32_bf16(a1, b0, acc[1][0], 0, 0, 0);
    acc[1][1] = __builtin_amdgcn_mfma_f32_16x16x32_bf16(a1, b1, acc[1][1], 0, 0, 0);
  }

  // C/D layout: col = lane&15, row = (lane>>4)*4 + reg  (verified m89/m91)
  int col = lane & 15, rb = (lane >> 4) * 4;
#pragma unroll
  for (int mi = 0; mi < 2; mi++)
#pragma unroll
    for (int ni = 0; ni < 2; ni++)
#pragma unroll
      for (int r = 0; r < 4; r++) {
        int gm = m0 + wm * 32 + mi * 16 + rb + r;
        int gn = n0 + wn * 32 + ni * 16 + col;
        float v = acc[mi][ni][r];
        if (bias) v += bias[gn];
        if (resid) v += resid[(long)gm * N + gn];
        if (relu) v = fmaxf(v, 0.f);
        if (CF32) ((float*)Cv)[(long)gm * N + gn] = v;
        else      ((u16*)Cv)[(long)gm * N + gn] = f2bf(v);
      }
}

// ------------- causal flash attention (fp32 vector), 1 wave per q-row -------------
// QKV layout (bf16): [B*S][3072], q at h*64, k at 1024+h*64, v at 2048+h*64.
__global__ __launch_bounds__(256) void attn_k(const u16* __restrict__ QKV,
                                              u16* __restrict__ out) {
  int b = blockIdx.z, h = blockIdx.y, qg = blockIdx.x;
  int tid = threadIdx.x, wave = tid >> 6, lane = tid & 63;
  int r = qg * 4 + wave;
  const u16* base = QKV + (long)b * S_ * 3072;

  __shared__ float Kt[64][65];  // Kt[d][t]
  __shared__ float Vt[64][69];  // Vt[t][d]
  __shared__ float qs[4][64];
  __shared__ float wb[4][64];

  qs[wave][lane] = bf2f(base[(long)r * 3072 + h * 64 + lane]);

  float m = -INFINITY, l = 0.f, o = 0.f;
  int nchunks = ((qg * 4 + 3) >> 6) + 1;  // uniform across the 4 waves
  int srow = tid >> 2;        // t within chunk
  int scol = (tid & 3) * 16;  // d base

  for (int c = 0; c < nchunks; c++) {
    int t0 = c * 64;
    __syncthreads();
    const u16* krow = base + (long)(t0 + srow) * 3072 + 1024 + h * 64 + scol;
    const u16* vrow = base + (long)(t0 + srow) * 3072 + 2048 + h * 64 + scol;
    u16x8 k0 = *(const u16x8*)krow;
    u16x8 k1 = *(const u16x8*)(krow + 8);
    u16x8 v0 = *(const u16x8*)vrow;
    u16x8 v1 = *(const u16x8*)(vrow + 8);
#pragma unroll
    for (int j = 0; j < 8; j++) {
      Kt[scol + j][srow] = bf2f(k0[j]);
      Kt[scol + 8 + j][srow] = bf2f(k1[j]);
      Vt[srow][scol + j] = bf2f(v0[j]);
      Vt[srow][scol + 8 + j] = bf2f(v1[j]);
    }
    __syncthreads();

    float s = 0.f;
#pragma unroll
    for (int d = 0; d < 64; d++) s += qs[wave][d] * Kt[d][lane];
    int t = t0 + lane;
    s = (t <= r) ? s * 0.03125f : -INFINITY;  // scale = E^-0.5 = 1/32

    float mx = s;
#pragma unroll
    for (int off = 32; off > 0; off >>= 1) mx = fmaxf(mx, __shfl_xor(mx, off));
    float mnew = fmaxf(m, mx);
    float p = __expf(s - mnew);
    float ps = p;
#pragma unroll
    for (int off = 32; off > 0; off >>= 1) ps += __shfl_xor(ps, off);
    float alpha = __expf(m - mnew);
    l = l * alpha + ps;
    m = mnew;
    wb[wave][lane] = p;
    o *= alpha;
    __syncthreads();

#pragma unroll
    for (int t2 = 0; t2 < 64; t2++) o += wb[wave][t2] * Vt[t2][lane];
  }
  out[((long)b * S_ + r) * 1024 + h * 64 + lane] = f2bf(o / l);
}

extern "C" void kernel_launch(void* const* d_in, const int* in_sizes, int n_in,
                              void* d_out, int out_size, void* d_ws, size_t ws_size,
                              hipStream_t stream) {
  (void)in_sizes; (void)n_in; (void)out_size; (void)ws_size;
  const float* x  = (const float*)d_in[0];
  const float* Wq = (const float*)d_in[1];
  const float* Wk = (const float*)d_in[2];
  const float* Wv = (const float*)d_in[3];
  const float* Wo = (const float*)d_in[4];
  const float* bo = (const float*)d_in[5];
  const float* W1 = (const float*)d_in[6];
  const float* b1 = (const float*)d_in[7];
  const float* W2 = (const float*)d_in[8];
  const float* b2 = (const float*)d_in[9];
  float* out = (float*)d_out;  // reference output dtype = fp32

  char* ws = (char*)d_ws;
  // region A (64 MiB): QKV bf16 (48 MiB) + attn bf16 (16 MiB); later reused as h bf16 (64 MiB)
  u16*   QKV  = (u16*)(ws);                  // 8192*3072 bf16
  u16*   attn = (u16*)(ws + 50331648);       // 8192*1024 bf16
  u16*   hbuf = (u16*)(ws);                  // 8192*4096 bf16 (overlay of region A)
  float* x1   = (float*)(ws + 67108864);     // 8192*1024 fp32 (32 MiB)
  u16*   WT   = (u16*)(ws + 100663296);      // 3072*1024 bf16 (q|k|v heads transposed)
  u16*   WoT  = (u16*)(ws + 106954752);      // 1024*1024 bf16
  u16*   W1T  = (u16*)(ws + 109051904);      // 4096*1024 bf16
  u16*   W2T  = (u16*)(ws + 117440512);      // 1024*4096 bf16
  // end: 125829120 bytes = 120 MiB

  // weight transposes+casts to bf16 [N,K]
  castT_k<<<dim3(2, 32, 16), 256, 0, stream>>>(Wq, WT, 1024, 64);
  castT_k<<<dim3(2, 32, 16), 256, 0, stream>>>(Wk, WT + 1048576, 1024, 64);
  castT_k<<<dim3(2, 32, 16), 256, 0, stream>>>(Wv, WT + 2097152, 1024, 64);
  castT_k<<<dim3(32, 32, 1), 256, 0, stream>>>(Wo, WoT, 1024, 1024);
  castT_k<<<dim3(128, 32, 1), 256, 0, stream>>>(W1, W1T, 1024, 4096);
  castT_k<<<dim3(32, 128, 1), 256, 0, stream>>>(W2, W2T, 4096, 1024);

  // QKV = x @ [Wq|Wk|Wv]   [8192,3072] bf16
  gemm_bt<true, false><<<dim3(48, 128), 256, 0, stream>>>(x, WT, QKV, nullptr, nullptr, 8192, 3072, 1024, 0);
  // causal attention -> attn [8192,1024] bf16 (heads concatenated)
  attn_k<<<dim3(S_ / 4, H_, B_), 256, 0, stream>>>(QKV, attn);
  // x1 = x + attn @ Wo + bo   (fp32)
  gemm_bt<false, true><<<dim3(16, 128), 256, 0, stream>>>(attn, WoT, x1, bo, x, 8192, 1024, 1024, 0);
  // h = relu(x1 @ W1 + b1)   [8192,4096] bf16
  gemm_bt<true, false><<<dim3(64, 128), 256, 0, stream>>>(x1, W1T, hbuf, b1, nullptr, 8192, 4096, 1024, 1);
  // out = x1 + h @ W2 + b2   (fp32 -> d_out)
  gemm_bt<false, true><<<dim3(16, 128), 256, 0, stream>>>(hbuf, W2T, out, b2, x1, 8192, 1024, 4096, 0);
}

// Round 5
// 922.159 us; speedup vs baseline: 3.3887x; 3.3887x over previous
//
#include <hip/hip_runtime.h>
#include <stdint.h>

#define B_ 4
#define S_ 2048
#define E_ 1024
#define H_ 16
#define D_ 64

typedef unsigned short u16;
typedef u16 u16x8 __attribute__((ext_vector_type(8)));
typedef __bf16 bf16x8 __attribute__((ext_vector_type(8)));
typedef float f32x4 __attribute__((ext_vector_type(4)));

__device__ __forceinline__ float bf2f(u16 x) {
  unsigned int v = ((unsigned int)x) << 16;
  return __builtin_bit_cast(float, v);
}
__device__ __forceinline__ u16 f2bf(float f) {
  unsigned int u = __builtin_bit_cast(unsigned int, f);
  unsigned int r = (u + 0x7fffu + ((u >> 16) & 1u)) >> 16;
  return (u16)r;
}

// ------------- batched 32x32 transpose + fp32->bf16 cast: dst[C,R] = bf16(src[R,C]^T) -------------
__global__ __launch_bounds__(256) void castT_k(const float* __restrict__ src,
                                               u16* __restrict__ dst, int R, int C) {
  long bofs = (long)blockIdx.z * R * C;
  src += bofs; dst += bofs;
  __shared__ u16 t[32][33];
  int c0 = blockIdx.x * 32, r0 = blockIdx.y * 32;
  int lc = threadIdx.x & 31, lr8 = threadIdx.x >> 5;
#pragma unroll
  for (int i = 0; i < 4; i++) {
    int lr = lr8 + i * 8;
    t[lr][lc] = f2bf(src[(long)(r0 + lr) * C + c0 + lc]);
  }
  __syncthreads();
#pragma unroll
  for (int i = 0; i < 4; i++) {
    int lr = lr8 + i * 8;
    dst[(long)(c0 + lr) * R + r0 + lc] = t[lc][lr];
  }
}

// ------------- MFMA GEMM: C[M,N] = A[M,K] @ BT[N,K]^T (+bias,+resid,relu) -------------
template <bool AF32, bool CF32>
__global__ __launch_bounds__(256) void gemm_bt(const void* __restrict__ Av,
                                               const u16* __restrict__ BT,
                                               void* __restrict__ Cv,
                                               const float* __restrict__ bias,
                                               const float* __restrict__ resid,
                                               int M, int N, int K, int relu) {
  __shared__ u16 As[64][40];
  __shared__ u16 Bs[64][40];
  int m0 = blockIdx.y * 64, n0 = blockIdx.x * 64;
  int tid = threadIdx.x;
  int wave = tid >> 6, lane = tid & 63;
  int wm = wave >> 1, wn = wave & 1;
  int srow = tid >> 2, scol = (tid & 3) * 8;
  const u16* Bp = BT + (long)(n0 + srow) * K + scol;

  f32x4 acc[2][2] = {};

  int kf = (lane >> 4) * 8;
  int fr = lane & 15;

  for (int k0 = 0; k0 < K; k0 += 32) {
    __syncthreads();
    if (AF32) {
      const float* Ap = (const float*)Av + (long)(m0 + srow) * K + scol + k0;
      f32x4 f0 = *(const f32x4*)Ap;
      f32x4 f1 = *(const f32x4*)(Ap + 4);
      u16x8 t;
#pragma unroll
      for (int j = 0; j < 4; j++) { t[j] = f2bf(f0[j]); t[j + 4] = f2bf(f1[j]); }
      *(u16x8*)(&As[srow][scol]) = t;
    } else {
      const u16* Ap = (const u16*)Av + (long)(m0 + srow) * K + scol + k0;
      *(u16x8*)(&As[srow][scol]) = *(const u16x8*)Ap;
    }
    *(u16x8*)(&Bs[srow][scol]) = *(const u16x8*)(Bp + k0);
    __syncthreads();
    bf16x8 a0 = __builtin_bit_cast(bf16x8, *(const u16x8*)&As[wm * 32 + fr][kf]);
    bf16x8 a1 = __builtin_bit_cast(bf16x8, *(const u16x8*)&As[wm * 32 + 16 + fr][kf]);
    bf16x8 b0 = __builtin_bit_cast(bf16x8, *(const u16x8*)&Bs[wn * 32 + fr][kf]);
    bf16x8 b1 = __builtin_bit_cast(bf16x8, *(const u16x8*)&Bs[wn * 32 + 16 + fr][kf]);
    acc[0][0] = __builtin_amdgcn_mfma_f32_16x16x32_bf16(a0, b0, acc[0][0], 0, 0, 0);
    acc[0][1] = __builtin_amdgcn_mfma_f32_16x16x32_bf16(a0, b1, acc[0][1], 0, 0, 0);
    acc[1][0] = __builtin_amdgcn_mfma_f32_16x16x32_bf16(a1, b0, acc[1][0], 0, 0, 0);
    acc[1][1] = __builtin_amdgcn_mfma_f32_16x16x32_bf16(a1, b1, acc[1][1], 0, 0, 0);
  }

  int col = lane & 15, rb = (lane >> 4) * 4;
#pragma unroll
  for (int mi = 0; mi < 2; mi++)
#pragma unroll
    for (int ni = 0; ni < 2; ni++)
#pragma unroll
      for (int r = 0; r < 4; r++) {
        int gm = m0 + wm * 32 + mi * 16 + rb + r;
        int gn = n0 + wn * 32 + ni * 16 + col;
        float v = acc[mi][ni][r];
        if (bias) v += bias[gn];
        if (resid) v += resid[(long)gm * N + gn];
        if (relu) v = fmaxf(v, 0.f);
        if (CF32) ((float*)Cv)[(long)gm * N + gn] = v;
        else      ((u16*)Cv)[(long)gm * N + gn] = f2bf(v);
      }
}

// ------------- MFMA causal flash attention -------------
// Block = (b, h, 64-row q-tile), 4 waves; wave wq owns q-rows wq*16..wq*16+15.
// QKV (bf16): [B*S][3072], q at h*64, k at 1024+h*64, v at 2048+h*64.
__global__ __launch_bounds__(256) void attn_mfma(const u16* __restrict__ QKV,
                                                 u16* __restrict__ attn) {
  int qt = blockIdx.x, h = blockIdx.y, b = blockIdx.z;
  int tid = threadIdx.x;
  int wq = tid >> 6, lane = tid & 63;
  int fr = lane & 15, quad = lane >> 4;
  int kf = quad * 8;

  __shared__ u16 Qs[64][72];       // Q[q][d], scaled by 1/32
  __shared__ u16 Ks[64][72];       // K[t][d]
  __shared__ u16 Vt[64][74];       // V transposed: Vt[d][t]
  __shared__ u16 Ps[4][16][72];    // per-wave P[q][t]

  const u16* base = QKV + (long)b * S_ * 3072;
  int st = tid >> 2;               // staging row 0..63
  int sd = (tid & 3) * 16;         // staging col base

  {  // stage Q scaled by 1/32 (= E^-0.5), exact exponent shift in fp32
    const u16* qr = base + (long)(qt * 64 + st) * 3072 + h * 64 + sd;
    u16x8 a = *(const u16x8*)qr, d = *(const u16x8*)(qr + 8);
    u16x8 oa, od;
#pragma unroll
    for (int j = 0; j < 8; j++) {
      oa[j] = f2bf(bf2f(a[j]) * 0.03125f);
      od[j] = f2bf(bf2f(d[j]) * 0.03125f);
    }
    *(u16x8*)&Qs[st][sd] = oa;
    *(u16x8*)&Qs[st][sd + 8] = od;
  }
  __syncthreads();
  // Q A-frags preloaded once (A[m=fr][k=quad*8+j], +32 for second k-step)
  bf16x8 qf0 = __builtin_bit_cast(bf16x8, *(const u16x8*)&Qs[wq * 16 + fr][kf]);
  bf16x8 qf1 = __builtin_bit_cast(bf16x8, *(const u16x8*)&Qs[wq * 16 + fr][32 + kf]);

  f32x4 acc[4] = {};
  float m[4], l[4];
#pragma unroll
  for (int r = 0; r < 4; r++) { m[r] = -INFINITY; l[r] = 0.f; }

  for (int c = 0; c <= qt; c++) {
    int t0 = c * 64;
    __syncthreads();
    {  // stage K row-major, V transposed
      const u16* kr = base + (long)(t0 + st) * 3072 + 1024 + h * 64 + sd;
      u16x8 k0 = *(const u16x8*)kr, k1 = *(const u16x8*)(kr + 8);
      u16x8 v0 = *(const u16x8*)(kr + 1024), v1 = *(const u16x8*)(kr + 1032);
      *(u16x8*)&Ks[st][sd] = k0;
      *(u16x8*)&Ks[st][sd + 8] = k1;
#pragma unroll
      for (int j = 0; j < 8; j++) {
        Vt[sd + j][st] = v0[j];
        Vt[sd + 8 + j][st] = v1[j];
      }
    }
    __syncthreads();

    // S = Q K^T : 4 n-tiles (t) x 2 k-steps (d)
    f32x4 sc[4] = {};
#pragma unroll
    for (int nt = 0; nt < 4; nt++) {
      bf16x8 b0 = __builtin_bit_cast(bf16x8, *(const u16x8*)&Ks[nt * 16 + fr][kf]);
      bf16x8 b1 = __builtin_bit_cast(bf16x8, *(const u16x8*)&Ks[nt * 16 + fr][32 + kf]);
      sc[nt] = __builtin_amdgcn_mfma_f32_16x16x32_bf16(qf0, b0, sc[nt], 0, 0, 0);
      sc[nt] = __builtin_amdgcn_mfma_f32_16x16x32_bf16(qf1, b1, sc[nt], 0, 0, 0);
    }

    if (c == qt) {  // diagonal chunk: mask t_local > q_local
      int qloc = wq * 16 + quad * 4;
#pragma unroll
      for (int nt = 0; nt < 4; nt++)
#pragma unroll
        for (int r = 0; r < 4; r++)
          if (nt * 16 + fr > qloc + r) sc[nt][r] = -1e30f;
    }

    // online softmax (row r lives in 16 lanes of this quad; reduce via xor 1,2,4,8)
    float al[4], ps[4];
#pragma unroll
    for (int r = 0; r < 4; r++) {
      float v = fmaxf(fmaxf(sc[0][r], sc[1][r]), fmaxf(sc[2][r], sc[3][r]));
#pragma unroll
      for (int off = 1; off < 16; off <<= 1) v = fmaxf(v, __shfl_xor(v, off));
      float mn = fmaxf(m[r], v);
      al[r] = __expf(m[r] - mn);
      m[r] = mn;
      ps[r] = 0.f;
    }
#pragma unroll
    for (int nt = 0; nt < 4; nt++)
#pragma unroll
      for (int r = 0; r < 4; r++) {
        float p = __expf(sc[nt][r] - m[r]);
        sc[nt][r] = p;
        ps[r] += p;
      }
#pragma unroll
    for (int r = 0; r < 4; r++) {
#pragma unroll
      for (int off = 1; off < 16; off <<= 1) ps[r] += __shfl_xor(ps[r], off);
      l[r] = l[r] * al[r] + ps[r];
#pragma unroll
      for (int nt = 0; nt < 4; nt++) acc[nt][r] *= al[r];
    }

    // P: C-layout -> LDS -> A-layout (guide-verified transform)
#pragma unroll
    for (int nt = 0; nt < 4; nt++)
#pragma unroll
      for (int r = 0; r < 4; r++)
        Ps[wq][quad * 4 + r][nt * 16 + fr] = f2bf(sc[nt][r]);
    __syncthreads();

    bf16x8 pa0 = __builtin_bit_cast(bf16x8, *(const u16x8*)&Ps[wq][fr][kf]);
    bf16x8 pa1 = __builtin_bit_cast(bf16x8, *(const u16x8*)&Ps[wq][fr][32 + kf]);
#pragma unroll
    for (int nt = 0; nt < 4; nt++) {
      bf16x8 vb0 = __builtin_bit_cast(bf16x8, *(const u16x8*)&Vt[nt * 16 + fr][kf]);
      bf16x8 vb1 = __builtin_bit_cast(bf16x8, *(const u16x8*)&Vt[nt * 16 + fr][32 + kf]);
      acc[nt] = __builtin_amdgcn_mfma_f32_16x16x32_bf16(pa0, vb0, acc[nt], 0, 0, 0);
      acc[nt] = __builtin_amdgcn_mfma_f32_16x16x32_bf16(pa1, vb1, acc[nt], 0, 0, 0);
    }
  }

  long row = (long)b * S_ + qt * 64 + wq * 16 + quad * 4;
#pragma unroll
  for (int nt = 0; nt < 4; nt++)
#pragma unroll
    for (int r = 0; r < 4; r++)
      attn[(row + r) * 1024 + h * 64 + nt * 16 + fr] = f2bf(acc[nt][r] / l[r]);
}

extern "C" void kernel_launch(void* const* d_in, const int* in_sizes, int n_in,
                              void* d_out, int out_size, void* d_ws, size_t ws_size,
                              hipStream_t stream) {
  (void)in_sizes; (void)n_in; (void)out_size; (void)ws_size;
  const float* x  = (const float*)d_in[0];
  const float* Wq = (const float*)d_in[1];
  const float* Wk = (const float*)d_in[2];
  const float* Wv = (const float*)d_in[3];
  const float* Wo = (const float*)d_in[4];
  const float* bo = (const float*)d_in[5];
  const float* W1 = (const float*)d_in[6];
  const float* b1 = (const float*)d_in[7];
  const float* W2 = (const float*)d_in[8];
  const float* b2 = (const float*)d_in[9];
  float* out = (float*)d_out;  // reference output dtype = fp32

  char* ws = (char*)d_ws;
  u16*   QKV  = (u16*)(ws);                  // 8192*3072 bf16
  u16*   attn = (u16*)(ws + 50331648);       // 8192*1024 bf16
  u16*   hbuf = (u16*)(ws);                  // 8192*4096 bf16 (overlay of region A)
  float* x1   = (float*)(ws + 67108864);     // 8192*1024 fp32
  u16*   WT   = (u16*)(ws + 100663296);      // 3072*1024 bf16 (q|k|v heads transposed)
  u16*   WoT  = (u16*)(ws + 106954752);      // 1024*1024 bf16
  u16*   W1T  = (u16*)(ws + 109051904);      // 4096*1024 bf16
  u16*   W2T  = (u16*)(ws + 117440512);      // 1024*4096 bf16

  castT_k<<<dim3(2, 32, 16), 256, 0, stream>>>(Wq, WT, 1024, 64);
  castT_k<<<dim3(2, 32, 16), 256, 0, stream>>>(Wk, WT + 1048576, 1024, 64);
  castT_k<<<dim3(2, 32, 16), 256, 0, stream>>>(Wv, WT + 2097152, 1024, 64);
  castT_k<<<dim3(32, 32, 1), 256, 0, stream>>>(Wo, WoT, 1024, 1024);
  castT_k<<<dim3(128, 32, 1), 256, 0, stream>>>(W1, W1T, 1024, 4096);
  castT_k<<<dim3(32, 128, 1), 256, 0, stream>>>(W2, W2T, 4096, 1024);

  // QKV = x @ [Wq|Wk|Wv]   [8192,3072] bf16
  gemm_bt<true, false><<<dim3(48, 128), 256, 0, stream>>>(x, WT, QKV, nullptr, nullptr, 8192, 3072, 1024, 0);
  // causal attention -> attn [8192,1024] bf16
  attn_mfma<<<dim3(S_ / 64, H_, B_), 256, 0, stream>>>(QKV, attn);
  // x1 = x + attn @ Wo + bo   (fp32)
  gemm_bt<false, true><<<dim3(16, 128), 256, 0, stream>>>(attn, WoT, x1, bo, x, 8192, 1024, 1024, 0);
  // h = relu(x1 @ W1 + b1)   [8192,4096] bf16
  gemm_bt<true, false><<<dim3(64, 128), 256, 0, stream>>>(x1, W1T, hbuf, b1, nullptr, 8192, 4096, 1024, 1);
  // out = x1 + h @ W2 + b2   (fp32 -> d_out)
  gemm_bt<false, true><<<dim3(16, 128), 256, 0, stream>>>(hbuf, W2T, out, b2, x1, 8192, 1024, 4096, 0);
}

// Round 6
// 848.127 us; speedup vs baseline: 3.6845x; 1.0873x over previous
//
#include <hip/hip_runtime.h>
#include <stdint.h>

#define B_ 4
#define S_ 2048
#define E_ 1024
#define H_ 16
#define D_ 64

typedef unsigned short u16;
typedef u16 u16x8 __attribute__((ext_vector_type(8)));
typedef __bf16 bf16x8 __attribute__((ext_vector_type(8)));
typedef float f32x4 __attribute__((ext_vector_type(4)));

__device__ __forceinline__ float bf2f(u16 x) {
  unsigned int v = ((unsigned int)x) << 16;
  return __builtin_bit_cast(float, v);
}
__device__ __forceinline__ u16 f2bf(float f) {
  unsigned int u = __builtin_bit_cast(unsigned int, f);
  unsigned int r = (u + 0x7fffu + ((u >> 16) & 1u)) >> 16;
  return (u16)r;
}

// async global->LDS, 16B per lane; LDS dest = wave-uniform base + lane*16 (m97/m104)
__device__ __forceinline__ void gl2lds16(const u16* g, u16* l) {
  __builtin_amdgcn_global_load_lds(
      (const __attribute__((address_space(1))) void*)g,
      (__attribute__((address_space(3))) void*)l, 16, 0, 0);
}

// ------------- elementwise fp32->bf16 cast -------------
__global__ __launch_bounds__(256) void cast_bf16_k(const float* __restrict__ src,
                                                   u16* __restrict__ dst, long n) {
  long i = ((long)blockIdx.x * 256 + threadIdx.x) * 8;
  if (i + 8 <= n) {
    f32x4 a = *(const f32x4*)(src + i), b = *(const f32x4*)(src + i + 4);
    u16x8 o;
#pragma unroll
    for (int j = 0; j < 4; j++) { o[j] = f2bf(a[j]); o[j + 4] = f2bf(b[j]); }
    *(u16x8*)(dst + i) = o;
  }
}

// ------------- batched 32x32 transpose + fp32->bf16 cast: dst[C,R] = bf16(src[R,C]^T) -------------
__global__ __launch_bounds__(256) void castT_k(const float* __restrict__ src,
                                               u16* __restrict__ dst, int R, int C) {
  long bofs = (long)blockIdx.z * R * C;
  src += bofs; dst += bofs;
  __shared__ u16 t[32][33];
  int c0 = blockIdx.x * 32, r0 = blockIdx.y * 32;
  int lc = threadIdx.x & 31, lr8 = threadIdx.x >> 5;
#pragma unroll
  for (int i = 0; i < 4; i++) {
    int lr = lr8 + i * 8;
    t[lr][lc] = f2bf(src[(long)(r0 + lr) * C + c0 + lc]);
  }
  __syncthreads();
#pragma unroll
  for (int i = 0; i < 4; i++) {
    int lr = lr8 + i * 8;
    dst[(long)(c0 + lr) * R + r0 + lc] = t[lc][lr];
  }
}

// ------------- m97-style MFMA GEMM: C[M,N] = A[M,K] @ BT[N,K]^T (+bias,+resid,relu) ----
// 128x128 tile, 4 waves (2x2), each wave 64x64 via 4x4 mfma_f32_16x16x32_bf16.
// bf16 A staged via global_load_lds width=16; fp32 A staged via VGPR convert (m93-style).
template <bool AF32, bool CF32>
__global__ __launch_bounds__(256) void gemm128(const void* __restrict__ Av,
                                               const u16* __restrict__ BT,
                                               void* __restrict__ Cv,
                                               const float* __restrict__ bias,
                                               const float* __restrict__ resid,
                                               int M, int N, int K, int relu) {
  __shared__ u16 As[128 * 32];  // row-major [128][32], UNPADDED (global_load_lds lane order)
  __shared__ u16 Bs[128 * 32];
  const int tid = threadIdx.x;
  const int wave = tid >> 6, lane = tid & 63;
  const int m0 = blockIdx.y * 128, n0 = blockIdx.x * 128;
  const int wm = wave >> 1, wn = wave & 1;
  const int fr = lane & 15, quad = lane >> 4;

  f32x4 acc[4][4] = {};

  // async staging map: wave w, inst j: rows w*32+j*16 + lane/4, kcol (lane&3)*8
  const int srow = wave * 32 + (lane >> 2);
  const int skcol = (lane & 3) * 8;

  for (int k0 = 0; k0 < K; k0 += 32) {
    __syncthreads();
    if (AF32) {
      // VGPR staging: thread t -> row t>>1, k-half (t&1)*16
      const float* Ap = (const float*)Av + (long)(m0 + (tid >> 1)) * K + k0 + (tid & 1) * 16;
      f32x4 f0 = *(const f32x4*)Ap, f1 = *(const f32x4*)(Ap + 4);
      f32x4 f2 = *(const f32x4*)(Ap + 8), f3 = *(const f32x4*)(Ap + 12);
      u16x8 p0, p1;
#pragma unroll
      for (int j = 0; j < 4; j++) {
        p0[j] = f2bf(f0[j]); p0[j + 4] = f2bf(f1[j]);
        p1[j] = f2bf(f2[j]); p1[j + 4] = f2bf(f3[j]);
      }
      *(u16x8*)&As[(tid >> 1) * 32 + (tid & 1) * 16] = p0;
      *(u16x8*)&As[(tid >> 1) * 32 + (tid & 1) * 16 + 8] = p1;
    } else {
      const u16* Ag = (const u16*)Av + (long)(m0 + srow) * K + k0 + skcol;
      gl2lds16(Ag, &As[(wave * 32) * 32]);
      gl2lds16(Ag + 16 * (long)K, &As[(wave * 32 + 16) * 32]);
    }
    {
      const u16* Bg = BT + (long)(n0 + srow) * K + k0 + skcol;
      gl2lds16(Bg, &Bs[(wave * 32) * 32]);
      gl2lds16(Bg + 16 * (long)K, &Bs[(wave * 32 + 16) * 32]);
    }
    __syncthreads();

    bf16x8 af[4], bfr[4];
#pragma unroll
    for (int mi = 0; mi < 4; mi++)
      af[mi] = __builtin_bit_cast(bf16x8, *(const u16x8*)&As[(wm * 64 + mi * 16 + fr) * 32 + quad * 8]);
#pragma unroll
    for (int ni = 0; ni < 4; ni++)
      bfr[ni] = __builtin_bit_cast(bf16x8, *(const u16x8*)&Bs[(wn * 64 + ni * 16 + fr) * 32 + quad * 8]);
#pragma unroll
    for (int mi = 0; mi < 4; mi++)
#pragma unroll
      for (int ni = 0; ni < 4; ni++)
        acc[mi][ni] = __builtin_amdgcn_mfma_f32_16x16x32_bf16(af[mi], bfr[ni], acc[mi][ni], 0, 0, 0);
  }

  // C/D layout: col = lane&15 (n), row = quad*4 + r (m)
#pragma unroll
  for (int mi = 0; mi < 4; mi++)
#pragma unroll
    for (int ni = 0; ni < 4; ni++)
#pragma unroll
      for (int r = 0; r < 4; r++) {
        int gm = m0 + wm * 64 + mi * 16 + quad * 4 + r;
        int gn = n0 + wn * 64 + ni * 16 + fr;
        float v = acc[mi][ni][r];
        if (bias) v += bias[gn];
        if (resid) v += resid[(long)gm * N + gn];
        if (relu) v = fmaxf(v, 0.f);
        if (CF32) ((float*)Cv)[(long)gm * N + gn] = v;
        else      ((u16*)Cv)[(long)gm * N + gn] = f2bf(v);
      }
}

// ------------- MFMA causal flash attention (unchanged from round 5) -------------
__global__ __launch_bounds__(256) void attn_mfma(const u16* __restrict__ QKV,
                                                 u16* __restrict__ attn) {
  int qt = blockIdx.x, h = blockIdx.y, b = blockIdx.z;
  int tid = threadIdx.x;
  int wq = tid >> 6, lane = tid & 63;
  int fr = lane & 15, quad = lane >> 4;
  int kf = quad * 8;

  __shared__ u16 Qs[64][72];
  __shared__ u16 Ks[64][72];
  __shared__ u16 Vt[64][74];
  __shared__ u16 Ps[4][16][72];

  const u16* base = QKV + (long)b * S_ * 3072;
  int st = tid >> 2;
  int sd = (tid & 3) * 16;

  {
    const u16* qr = base + (long)(qt * 64 + st) * 3072 + h * 64 + sd;
    u16x8 a = *(const u16x8*)qr, d = *(const u16x8*)(qr + 8);
    u16x8 oa, od;
#pragma unroll
    for (int j = 0; j < 8; j++) {
      oa[j] = f2bf(bf2f(a[j]) * 0.03125f);
      od[j] = f2bf(bf2f(d[j]) * 0.03125f);
    }
    *(u16x8*)&Qs[st][sd] = oa;
    *(u16x8*)&Qs[st][sd + 8] = od;
  }
  __syncthreads();
  bf16x8 qf0 = __builtin_bit_cast(bf16x8, *(const u16x8*)&Qs[wq * 16 + fr][kf]);
  bf16x8 qf1 = __builtin_bit_cast(bf16x8, *(const u16x8*)&Qs[wq * 16 + fr][32 + kf]);

  f32x4 acc[4] = {};
  float m[4], l[4];
#pragma unroll
  for (int r = 0; r < 4; r++) { m[r] = -INFINITY; l[r] = 0.f; }

  for (int c = 0; c <= qt; c++) {
    int t0 = c * 64;
    __syncthreads();
    {
      const u16* kr = base + (long)(t0 + st) * 3072 + 1024 + h * 64 + sd;
      u16x8 k0 = *(const u16x8*)kr, k1 = *(const u16x8*)(kr + 8);
      u16x8 v0 = *(const u16x8*)(kr + 1024), v1 = *(const u16x8*)(kr + 1032);
      *(u16x8*)&Ks[st][sd] = k0;
      *(u16x8*)&Ks[st][sd + 8] = k1;
#pragma unroll
      for (int j = 0; j < 8; j++) {
        Vt[sd + j][st] = v0[j];
        Vt[sd + 8 + j][st] = v1[j];
      }
    }
    __syncthreads();

    f32x4 sc[4] = {};
#pragma unroll
    for (int nt = 0; nt < 4; nt++) {
      bf16x8 b0 = __builtin_bit_cast(bf16x8, *(const u16x8*)&Ks[nt * 16 + fr][kf]);
      bf16x8 b1 = __builtin_bit_cast(bf16x8, *(const u16x8*)&Ks[nt * 16 + fr][32 + kf]);
      sc[nt] = __builtin_amdgcn_mfma_f32_16x16x32_bf16(qf0, b0, sc[nt], 0, 0, 0);
      sc[nt] = __builtin_amdgcn_mfma_f32_16x16x32_bf16(qf1, b1, sc[nt], 0, 0, 0);
    }

    if (c == qt) {
      int qloc = wq * 16 + quad * 4;
#pragma unroll
      for (int nt = 0; nt < 4; nt++)
#pragma unroll
        for (int r = 0; r < 4; r++)
          if (nt * 16 + fr > qloc + r) sc[nt][r] = -1e30f;
    }

    float al[4], ps[4];
#pragma unroll
    for (int r = 0; r < 4; r++) {
      float v = fmaxf(fmaxf(sc[0][r], sc[1][r]), fmaxf(sc[2][r], sc[3][r]));
#pragma unroll
      for (int off = 1; off < 16; off <<= 1) v = fmaxf(v, __shfl_xor(v, off));
      float mn = fmaxf(m[r], v);
      al[r] = __expf(m[r] - mn);
      m[r] = mn;
      ps[r] = 0.f;
    }
#pragma unroll
    for (int nt = 0; nt < 4; nt++)
#pragma unroll
      for (int r = 0; r < 4; r++) {
        float p = __expf(sc[nt][r] - m[r]);
        sc[nt][r] = p;
        ps[r] += p;
      }
#pragma unroll
    for (int r = 0; r < 4; r++) {
#pragma unroll
      for (int off = 1; off < 16; off <<= 1) ps[r] += __shfl_xor(ps[r], off);
      l[r] = l[r] * al[r] + ps[r];
#pragma unroll
      for (int nt = 0; nt < 4; nt++) acc[nt][r] *= al[r];
    }

#pragma unroll
    for (int nt = 0; nt < 4; nt++)
#pragma unroll
      for (int r = 0; r < 4; r++)
        Ps[wq][quad * 4 + r][nt * 16 + fr] = f2bf(sc[nt][r]);
    __syncthreads();

    bf16x8 pa0 = __builtin_bit_cast(bf16x8, *(const u16x8*)&Ps[wq][fr][kf]);
    bf16x8 pa1 = __builtin_bit_cast(bf16x8, *(const u16x8*)&Ps[wq][fr][32 + kf]);
#pragma unroll
    for (int nt = 0; nt < 4; nt++) {
      bf16x8 vb0 = __builtin_bit_cast(bf16x8, *(const u16x8*)&Vt[nt * 16 + fr][kf]);
      bf16x8 vb1 = __builtin_bit_cast(bf16x8, *(const u16x8*)&Vt[nt * 16 + fr][32 + kf]);
      acc[nt] = __builtin_amdgcn_mfma_f32_16x16x32_bf16(pa0, vb0, acc[nt], 0, 0, 0);
      acc[nt] = __builtin_amdgcn_mfma_f32_16x16x32_bf16(pa1, vb1, acc[nt], 0, 0, 0);
    }
  }

  long row = (long)b * S_ + qt * 64 + wq * 16 + quad * 4;
#pragma unroll
  for (int nt = 0; nt < 4; nt++)
#pragma unroll
    for (int r = 0; r < 4; r++)
      attn[(row + r) * 1024 + h * 64 + nt * 16 + fr] = f2bf(acc[nt][r] / l[r]);
}

extern "C" void kernel_launch(void* const* d_in, const int* in_sizes, int n_in,
                              void* d_out, int out_size, void* d_ws, size_t ws_size,
                              hipStream_t stream) {
  (void)in_sizes; (void)n_in; (void)out_size; (void)ws_size;
  const float* x  = (const float*)d_in[0];
  const float* Wq = (const float*)d_in[1];
  const float* Wk = (const float*)d_in[2];
  const float* Wv = (const float*)d_in[3];
  const float* Wo = (const float*)d_in[4];
  const float* bo = (const float*)d_in[5];
  const float* W1 = (const float*)d_in[6];
  const float* b1 = (const float*)d_in[7];
  const float* W2 = (const float*)d_in[8];
  const float* b2 = (const float*)d_in[9];
  float* out = (float*)d_out;  // fp32 output

  char* ws = (char*)d_ws;
  // lifetimes: QKV[gemm..attn], attn[attn..Wo-gemm], xb[cast..QKV-gemm],
  // hbuf[FFN1..FFN2] overlays QKV+attn, x1[Wo-gemm..FFN2] (xb overlays x1 2nd half, disjoint)
  u16*   QKV  = (u16*)(ws);                  // [0, 48MiB)
  u16*   attn = (u16*)(ws + 50331648);       // [48MiB, 64MiB)
  u16*   hbuf = (u16*)(ws);                  // [0, 64MiB)
  float* x1   = (float*)(ws + 67108864);     // [64MiB, 96MiB) fp32
  u16*   xb   = (u16*)(ws + 83886080);       // [80MiB, 96MiB) bf16 (dead before x1 written)
  u16*   WT   = (u16*)(ws + 100663296);      // 6MiB
  u16*   WoT  = (u16*)(ws + 106954752);      // 2MiB
  u16*   W1T  = (u16*)(ws + 109051904);      // 8MiB
  u16*   W2T  = (u16*)(ws + 117440512);      // 8MiB -> ends 120MiB

  cast_bf16_k<<<4096, 256, 0, stream>>>(x, xb, (long)8192 * 1024);
  castT_k<<<dim3(2, 32, 16), 256, 0, stream>>>(Wq, WT, 1024, 64);
  castT_k<<<dim3(2, 32, 16), 256, 0, stream>>>(Wk, WT + 1048576, 1024, 64);
  castT_k<<<dim3(2, 32, 16), 256, 0, stream>>>(Wv, WT + 2097152, 1024, 64);
  castT_k<<<dim3(32, 32, 1), 256, 0, stream>>>(Wo, WoT, 1024, 1024);
  castT_k<<<dim3(128, 32, 1), 256, 0, stream>>>(W1, W1T, 1024, 4096);
  castT_k<<<dim3(32, 128, 1), 256, 0, stream>>>(W2, W2T, 4096, 1024);

  // QKV = xb @ [Wq|Wk|Wv]   [8192,3072] bf16
  gemm128<false, false><<<dim3(24, 64), 256, 0, stream>>>(xb, WT, QKV, nullptr, nullptr, 8192, 3072, 1024, 0);
  // causal attention -> attn [8192,1024] bf16
  attn_mfma<<<dim3(S_ / 64, H_, B_), 256, 0, stream>>>(QKV, attn);
  // x1 = x + attn @ Wo + bo   (fp32)
  gemm128<false, true><<<dim3(8, 64), 256, 0, stream>>>(attn, WoT, x1, bo, x, 8192, 1024, 1024, 0);
  // h = relu(x1 @ W1 + b1)   [8192,4096] bf16  (A fp32 via VGPR staging)
  gemm128<true, false><<<dim3(32, 64), 256, 0, stream>>>(x1, W1T, hbuf, b1, nullptr, 8192, 4096, 1024, 1);
  // out = x1 + h @ W2 + b2   (fp32 -> d_out)
  gemm128<false, true><<<dim3(8, 64), 256, 0, stream>>>(hbuf, W2T, out, b2, x1, 8192, 1024, 4096, 0);
}

// Round 7
// 678.531 us; speedup vs baseline: 4.6054x; 1.2499x over previous
//
#include <hip/hip_runtime.h>
#include <stdint.h>

#define B_ 4
#define S_ 2048
#define E_ 1024
#define H_ 16
#define D_ 64

typedef unsigned short u16;
typedef u16 u16x8 __attribute__((ext_vector_type(8)));
typedef __bf16 bf16x8 __attribute__((ext_vector_type(8)));
typedef float f32x4 __attribute__((ext_vector_type(4)));

__device__ __forceinline__ float bf2f(u16 x) {
  unsigned int v = ((unsigned int)x) << 16;
  return __builtin_bit_cast(float, v);
}
__device__ __forceinline__ u16 f2bf(float f) {
  unsigned int u = __builtin_bit_cast(unsigned int, f);
  unsigned int r = (u + 0x7fffu + ((u >> 16) & 1u)) >> 16;
  return (u16)r;
}

// async global->LDS, 16B per lane; LDS dest = wave-uniform base + lane*16 (m97/m104)
__device__ __forceinline__ void gl2lds16(const u16* g, u16* l) {
  __builtin_amdgcn_global_load_lds(
      (const __attribute__((address_space(1))) void*)g,
      (__attribute__((address_space(3))) void*)l, 16, 0, 0);
}

// ------------- elementwise fp32->bf16 cast -------------
__global__ __launch_bounds__(256) void cast_bf16_k(const float* __restrict__ src,
                                                   u16* __restrict__ dst, long n) {
  long i = ((long)blockIdx.x * 256 + threadIdx.x) * 8;
  if (i + 8 <= n) {
    f32x4 a = *(const f32x4*)(src + i), b = *(const f32x4*)(src + i + 4);
    u16x8 o;
#pragma unroll
    for (int j = 0; j < 4; j++) { o[j] = f2bf(a[j]); o[j + 4] = f2bf(b[j]); }
    *(u16x8*)(dst + i) = o;
  }
}

// ------------- batched 32x32 transpose + fp32->bf16 cast: dst[C,R] = bf16(src[R,C]^T) -------------
__global__ __launch_bounds__(256) void castT_k(const float* __restrict__ src,
                                               u16* __restrict__ dst, int R, int C) {
  long bofs = (long)blockIdx.z * R * C;
  src += bofs; dst += bofs;
  __shared__ u16 t[32][33];
  int c0 = blockIdx.x * 32, r0 = blockIdx.y * 32;
  int lc = threadIdx.x & 31, lr8 = threadIdx.x >> 5;
#pragma unroll
  for (int i = 0; i < 4; i++) {
    int lr = lr8 + i * 8;
    t[lr][lc] = f2bf(src[(long)(r0 + lr) * C + c0 + lc]);
  }
  __syncthreads();
#pragma unroll
  for (int i = 0; i < 4; i++) {
    int lr = lr8 + i * 8;
    dst[(long)(c0 + lr) * R + r0 + lc] = t[lc][lr];
  }
}

// ------------- m97-style MFMA GEMM: C[M,N] = A[M,K] @ BT[N,K]^T (+bias,+resid,relu) ----
// 128x128 tile, 4 waves (2x2), each wave 64x64 via 4x4 mfma_f32_16x16x32_bf16.
// Cbf: optional second (bf16) store of the epilogue result.
template <bool AF32, bool CF32>
__global__ __launch_bounds__(256) void gemm128(const void* __restrict__ Av,
                                               const u16* __restrict__ BT,
                                               void* __restrict__ Cv,
                                               const float* __restrict__ bias,
                                               const float* __restrict__ resid,
                                               int M, int N, int K, int relu,
                                               u16* __restrict__ Cbf) {
  __shared__ u16 As[128 * 32];  // row-major [128][32], UNPADDED (global_load_lds lane order)
  __shared__ u16 Bs[128 * 32];
  const int tid = threadIdx.x;
  const int wave = tid >> 6, lane = tid & 63;
  const int m0 = blockIdx.y * 128, n0 = blockIdx.x * 128;
  const int wm = wave >> 1, wn = wave & 1;
  const int fr = lane & 15, quad = lane >> 4;

  f32x4 acc[4][4] = {};

  const int srow = wave * 32 + (lane >> 2);
  const int skcol = (lane & 3) * 8;

  for (int k0 = 0; k0 < K; k0 += 32) {
    __syncthreads();
    if (AF32) {
      const float* Ap = (const float*)Av + (long)(m0 + (tid >> 1)) * K + k0 + (tid & 1) * 16;
      f32x4 f0 = *(const f32x4*)Ap, f1 = *(const f32x4*)(Ap + 4);
      f32x4 f2 = *(const f32x4*)(Ap + 8), f3 = *(const f32x4*)(Ap + 12);
      u16x8 p0, p1;
#pragma unroll
      for (int j = 0; j < 4; j++) {
        p0[j] = f2bf(f0[j]); p0[j + 4] = f2bf(f1[j]);
        p1[j] = f2bf(f2[j]); p1[j + 4] = f2bf(f3[j]);
      }
      *(u16x8*)&As[(tid >> 1) * 32 + (tid & 1) * 16] = p0;
      *(u16x8*)&As[(tid >> 1) * 32 + (tid & 1) * 16 + 8] = p1;
    } else {
      const u16* Ag = (const u16*)Av + (long)(m0 + srow) * K + k0 + skcol;
      gl2lds16(Ag, &As[(wave * 32) * 32]);
      gl2lds16(Ag + 16 * (long)K, &As[(wave * 32 + 16) * 32]);
    }
    {
      const u16* Bg = BT + (long)(n0 + srow) * K + k0 + skcol;
      gl2lds16(Bg, &Bs[(wave * 32) * 32]);
      gl2lds16(Bg + 16 * (long)K, &Bs[(wave * 32 + 16) * 32]);
    }
    __syncthreads();

    bf16x8 af[4], bfr[4];
#pragma unroll
    for (int mi = 0; mi < 4; mi++)
      af[mi] = __builtin_bit_cast(bf16x8, *(const u16x8*)&As[(wm * 64 + mi * 16 + fr) * 32 + quad * 8]);
#pragma unroll
    for (int ni = 0; ni < 4; ni++)
      bfr[ni] = __builtin_bit_cast(bf16x8, *(const u16x8*)&Bs[(wn * 64 + ni * 16 + fr) * 32 + quad * 8]);
#pragma unroll
    for (int mi = 0; mi < 4; mi++)
#pragma unroll
      for (int ni = 0; ni < 4; ni++)
        acc[mi][ni] = __builtin_amdgcn_mfma_f32_16x16x32_bf16(af[mi], bfr[ni], acc[mi][ni], 0, 0, 0);
  }

#pragma unroll
  for (int mi = 0; mi < 4; mi++)
#pragma unroll
    for (int ni = 0; ni < 4; ni++)
#pragma unroll
      for (int r = 0; r < 4; r++) {
        int gm = m0 + wm * 64 + mi * 16 + quad * 4 + r;
        int gn = n0 + wn * 64 + ni * 16 + fr;
        float v = acc[mi][ni][r];
        if (bias) v += bias[gn];
        if (resid) v += resid[(long)gm * N + gn];
        if (relu) v = fmaxf(v, 0.f);
        if (CF32) ((float*)Cv)[(long)gm * N + gn] = v;
        else      ((u16*)Cv)[(long)gm * N + gn] = f2bf(v);
        if (Cbf) Cbf[(long)gm * N + gn] = f2bf(v);
      }
}

// ------------- MFMA causal flash attention, paired q-tiles for uniform work -------------
// Block p handles q-tiles (p, 31-p): (p+1)+(32-p) = 33 chunks uniformly.
__global__ __launch_bounds__(256) void attn_mfma3(const u16* __restrict__ QKV,
                                                  u16* __restrict__ attn) {
  int p = blockIdx.x, h = blockIdx.y, b = blockIdx.z;
  int tid = threadIdx.x;
  int wq = tid >> 6, lane = tid & 63;
  int fr = lane & 15, quad = lane >> 4;
  int kf = quad * 8;

  __shared__ u16 Qs[64][72];
  __shared__ u16 Ks[64][72];
  __shared__ u16 Vt[64][72];     // 72: 144B rows keep b128 reads 16B-aligned
  __shared__ u16 Ps[4][16][72];

  const u16* base = QKV + (long)b * S_ * 3072;
  int st = tid >> 2;
  int sd = (tid & 3) * 16;

  for (int ti = 0; ti < 2; ti++) {
    int qt = ti ? (31 - p) : p;

    {  // stage Q scaled by 1/32 (= E^-0.5)
      const u16* qr = base + (long)(qt * 64 + st) * 3072 + h * 64 + sd;
      u16x8 a = *(const u16x8*)qr, d = *(const u16x8*)(qr + 8);
      u16x8 oa, od;
#pragma unroll
      for (int j = 0; j < 8; j++) {
        oa[j] = f2bf(bf2f(a[j]) * 0.03125f);
        od[j] = f2bf(bf2f(d[j]) * 0.03125f);
      }
      *(u16x8*)&Qs[st][sd] = oa;
      *(u16x8*)&Qs[st][sd + 8] = od;
    }
    __syncthreads();
    bf16x8 qf0 = __builtin_bit_cast(bf16x8, *(const u16x8*)&Qs[wq * 16 + fr][kf]);
    bf16x8 qf1 = __builtin_bit_cast(bf16x8, *(const u16x8*)&Qs[wq * 16 + fr][32 + kf]);

    f32x4 acc[4] = {};
    float m[4], l[4];
#pragma unroll
    for (int r = 0; r < 4; r++) { m[r] = -INFINITY; l[r] = 0.f; }

    for (int c = 0; c <= qt; c++) {
      int t0 = c * 64;
      __syncthreads();  // protect Ks/Vt restage from previous chunk's readers
      {
        const u16* kr = base + (long)(t0 + st) * 3072 + 1024 + h * 64 + sd;
        u16x8 k0 = *(const u16x8*)kr, k1 = *(const u16x8*)(kr + 8);
        u16x8 v0 = *(const u16x8*)(kr + 1024), v1 = *(const u16x8*)(kr + 1032);
        *(u16x8*)&Ks[st][sd] = k0;
        *(u16x8*)&Ks[st][sd + 8] = k1;
#pragma unroll
        for (int j = 0; j < 8; j++) {
          Vt[sd + j][st] = v0[j];
          Vt[sd + 8 + j][st] = v1[j];
        }
      }
      __syncthreads();

      f32x4 sc[4] = {};
#pragma unroll
      for (int nt = 0; nt < 4; nt++) {
        bf16x8 b0 = __builtin_bit_cast(bf16x8, *(const u16x8*)&Ks[nt * 16 + fr][kf]);
        bf16x8 b1 = __builtin_bit_cast(bf16x8, *(const u16x8*)&Ks[nt * 16 + fr][32 + kf]);
        sc[nt] = __builtin_amdgcn_mfma_f32_16x16x32_bf16(qf0, b0, sc[nt], 0, 0, 0);
        sc[nt] = __builtin_amdgcn_mfma_f32_16x16x32_bf16(qf1, b1, sc[nt], 0, 0, 0);
      }

      if (c == qt) {  // diagonal chunk mask
        int qloc = wq * 16 + quad * 4;
#pragma unroll
        for (int nt = 0; nt < 4; nt++)
#pragma unroll
          for (int r = 0; r < 4; r++)
            if (nt * 16 + fr > qloc + r) sc[nt][r] = -1e30f;
      }

      float al[4], ps[4];
#pragma unroll
      for (int r = 0; r < 4; r++) {
        float v = fmaxf(fmaxf(sc[0][r], sc[1][r]), fmaxf(sc[2][r], sc[3][r]));
#pragma unroll
        for (int off = 1; off < 16; off <<= 1) v = fmaxf(v, __shfl_xor(v, off));
        float mn = fmaxf(m[r], v);
        al[r] = __expf(m[r] - mn);
        m[r] = mn;
        ps[r] = 0.f;
      }
#pragma unroll
      for (int nt = 0; nt < 4; nt++)
#pragma unroll
        for (int r = 0; r < 4; r++) {
          float pv = __expf(sc[nt][r] - m[r]);
          sc[nt][r] = pv;
          ps[r] += pv;
        }
#pragma unroll
      for (int r = 0; r < 4; r++) {
#pragma unroll
        for (int off = 1; off < 16; off <<= 1) ps[r] += __shfl_xor(ps[r], off);
        l[r] = l[r] * al[r] + ps[r];
#pragma unroll
        for (int nt = 0; nt < 4; nt++) acc[nt][r] *= al[r];
      }

      // P: C-layout -> per-wave LDS -> A-layout. No block barrier needed: Ps[wq]
      // is wave-private; compiler-inserted lgkmcnt orders the wave's write->read.
#pragma unroll
      for (int nt = 0; nt < 4; nt++)
#pragma unroll
        for (int r = 0; r < 4; r++)
          Ps[wq][quad * 4 + r][nt * 16 + fr] = f2bf(sc[nt][r]);

      bf16x8 pa0 = __builtin_bit_cast(bf16x8, *(const u16x8*)&Ps[wq][fr][kf]);
      bf16x8 pa1 = __builtin_bit_cast(bf16x8, *(const u16x8*)&Ps[wq][fr][32 + kf]);
#pragma unroll
      for (int nt = 0; nt < 4; nt++) {
        bf16x8 vb0 = __builtin_bit_cast(bf16x8, *(const u16x8*)&Vt[nt * 16 + fr][kf]);
        bf16x8 vb1 = __builtin_bit_cast(bf16x8, *(const u16x8*)&Vt[nt * 16 + fr][32 + kf]);
        acc[nt] = __builtin_amdgcn_mfma_f32_16x16x32_bf16(pa0, vb0, acc[nt], 0, 0, 0);
        acc[nt] = __builtin_amdgcn_mfma_f32_16x16x32_bf16(pa1, vb1, acc[nt], 0, 0, 0);
      }
    }

    long row = (long)b * S_ + qt * 64 + wq * 16 + quad * 4;
#pragma unroll
    for (int nt = 0; nt < 4; nt++)
#pragma unroll
      for (int r = 0; r < 4; r++)
        attn[(row + r) * 1024 + h * 64 + nt * 16 + fr] = f2bf(acc[nt][r] / l[r]);
  }
}

extern "C" void kernel_launch(void* const* d_in, const int* in_sizes, int n_in,
                              void* d_out, int out_size, void* d_ws, size_t ws_size,
                              hipStream_t stream) {
  (void)in_sizes; (void)n_in; (void)out_size;
  const float* x  = (const float*)d_in[0];
  const float* Wq = (const float*)d_in[1];
  const float* Wk = (const float*)d_in[2];
  const float* Wv = (const float*)d_in[3];
  const float* Wo = (const float*)d_in[4];
  const float* bo = (const float*)d_in[5];
  const float* W1 = (const float*)d_in[6];
  const float* b1 = (const float*)d_in[7];
  const float* W2 = (const float*)d_in[8];
  const float* b2 = (const float*)d_in[9];
  float* out = (float*)d_out;  // fp32 output

  char* ws = (char*)d_ws;
  u16*   QKV  = (u16*)(ws);                  // [0, 48MiB)
  u16*   attn = (u16*)(ws + 50331648);       // [48MiB, 64MiB)
  u16*   hbuf = (u16*)(ws);                  // [0, 64MiB)
  float* x1   = (float*)(ws + 67108864);     // [64MiB, 96MiB) fp32
  u16*   xb   = (u16*)(ws + 83886080);       // [80MiB, 96MiB) bf16 (dead before x1 written)
  u16*   WT   = (u16*)(ws + 100663296);      // 6MiB
  u16*   WoT  = (u16*)(ws + 106954752);      // 2MiB
  u16*   W1T  = (u16*)(ws + 109051904);      // 8MiB
  u16*   W2T  = (u16*)(ws + 117440512);      // 8MiB -> ends 120MiB
  u16*   x1b  = (u16*)(ws + 125829120);      // [120MiB, 136MiB) if ws allows
  bool bigws = ws_size >= (size_t)142606336; // 136 MiB

  cast_bf16_k<<<4096, 256, 0, stream>>>(x, xb, (long)8192 * 1024);
  castT_k<<<dim3(2, 32, 16), 256, 0, stream>>>(Wq, WT, 1024, 64);
  castT_k<<<dim3(2, 32, 16), 256, 0, stream>>>(Wk, WT + 1048576, 1024, 64);
  castT_k<<<dim3(2, 32, 16), 256, 0, stream>>>(Wv, WT + 2097152, 1024, 64);
  castT_k<<<dim3(32, 32, 1), 256, 0, stream>>>(Wo, WoT, 1024, 1024);
  castT_k<<<dim3(128, 32, 1), 256, 0, stream>>>(W1, W1T, 1024, 4096);
  castT_k<<<dim3(32, 128, 1), 256, 0, stream>>>(W2, W2T, 4096, 1024);

  // QKV = xb @ [Wq|Wk|Wv]   [8192,3072] bf16
  gemm128<false, false><<<dim3(24, 64), 256, 0, stream>>>(xb, WT, QKV, nullptr, nullptr, 8192, 3072, 1024, 0, nullptr);
  // causal attention -> attn [8192,1024] bf16
  attn_mfma3<<<dim3(16, H_, B_), 256, 0, stream>>>(QKV, attn);
  // x1 = x + attn @ Wo + bo   (fp32, + optional bf16 dual-store)
  gemm128<false, true><<<dim3(8, 64), 256, 0, stream>>>(attn, WoT, x1, bo, x, 8192, 1024, 1024, 0, bigws ? x1b : nullptr);
  // h = relu(x1 @ W1 + b1)   [8192,4096] bf16
  if (bigws)
    gemm128<false, false><<<dim3(32, 64), 256, 0, stream>>>(x1b, W1T, hbuf, b1, nullptr, 8192, 4096, 1024, 1, nullptr);
  else
    gemm128<true, false><<<dim3(32, 64), 256, 0, stream>>>(x1, W1T, hbuf, b1, nullptr, 8192, 4096, 1024, 1, nullptr);
  // out = x1 + h @ W2 + b2   (fp32 -> d_out)
  gemm128<false, true><<<dim3(8, 64), 256, 0, stream>>>(hbuf, W2T, out, b2, x1, 8192, 1024, 4096, 0, nullptr);
}

// Round 8
// 669.016 us; speedup vs baseline: 4.6709x; 1.0142x over previous
//
#include <hip/hip_runtime.h>
#include <stdint.h>

#define B_ 4
#define S_ 2048
#define E_ 1024
#define H_ 16
#define D_ 64

typedef unsigned short u16;
typedef u16 u16x8 __attribute__((ext_vector_type(8)));
typedef __bf16 bf16x8 __attribute__((ext_vector_type(8)));
typedef float f32x4 __attribute__((ext_vector_type(4)));

__device__ __forceinline__ float bf2f(u16 x) {
  unsigned int v = ((unsigned int)x) << 16;
  return __builtin_bit_cast(float, v);
}
__device__ __forceinline__ u16 f2bf(float f) {
  unsigned int u = __builtin_bit_cast(unsigned int, f);
  unsigned int r = (u + 0x7fffu + ((u >> 16) & 1u)) >> 16;
  return (u16)r;
}

// async global->LDS, 16B per lane; LDS dest = wave-uniform base + lane*16 (m97/m104)
__device__ __forceinline__ void gl2lds16(const u16* g, u16* l) {
  __builtin_amdgcn_global_load_lds(
      (const __attribute__((address_space(1))) void*)g,
      (__attribute__((address_space(3))) void*)l, 16, 0, 0);
}

// ------------- elementwise fp32->bf16 cast -------------
__global__ __launch_bounds__(256) void cast_bf16_k(const float* __restrict__ src,
                                                   u16* __restrict__ dst, long n) {
  long i = ((long)blockIdx.x * 256 + threadIdx.x) * 8;
  if (i + 8 <= n) {
    f32x4 a = *(const f32x4*)(src + i), b = *(const f32x4*)(src + i + 4);
    u16x8 o;
#pragma unroll
    for (int j = 0; j < 4; j++) { o[j] = f2bf(a[j]); o[j + 4] = f2bf(b[j]); }
    *(u16x8*)(dst + i) = o;
  }
}

// ------------- batched 32x32 transpose + fp32->bf16 cast: dst[C,R] = bf16(src[R,C]^T) -------------
__global__ __launch_bounds__(256) void castT_k(const float* __restrict__ src,
                                               u16* __restrict__ dst, int R, int C) {
  long bofs = (long)blockIdx.z * R * C;
  src += bofs; dst += bofs;
  __shared__ u16 t[32][33];
  int c0 = blockIdx.x * 32, r0 = blockIdx.y * 32;
  int lc = threadIdx.x & 31, lr8 = threadIdx.x >> 5;
#pragma unroll
  for (int i = 0; i < 4; i++) {
    int lr = lr8 + i * 8;
    t[lr][lc] = f2bf(src[(long)(r0 + lr) * C + c0 + lc]);
  }
  __syncthreads();
#pragma unroll
  for (int i = 0; i < 4; i++) {
    int lr = lr8 + i * 8;
    dst[(long)(c0 + lr) * R + r0 + lc] = t[lc][lr];
  }
}

// ------------- V transpose: VTg[b*16+h][d][t] = QKV[b*2048+t][2048 + h*64 + d] -------------
__global__ __launch_bounds__(256) void vT_k(const u16* __restrict__ QKV,
                                            u16* __restrict__ VTg) {
  int bh = blockIdx.z, d0 = blockIdx.y * 32, t0 = blockIdx.x * 32;
  int b = bh >> 4, h = bh & 15;
  __shared__ u16 t[32][33];
  int lc = threadIdx.x & 31, lr8 = threadIdx.x >> 5;
#pragma unroll
  for (int i = 0; i < 4; i++) {
    int lr = lr8 + i * 8;  // t within tile
    t[lr][lc] = QKV[(long)(b * S_ + t0 + lr) * 3072 + 2048 + h * 64 + d0 + lc];
  }
  __syncthreads();
#pragma unroll
  for (int i = 0; i < 4; i++) {
    int lr = lr8 + i * 8;  // d within tile
    VTg[((long)bh * 64 + d0 + lr) * S_ + t0 + lc] = t[lc][lr];
  }
}

// ------------- m97-style MFMA GEMM: C[M,N] = A[M,K] @ BT[N,K]^T (+bias,+resid,relu) ----
template <bool AF32, bool CF32>
__global__ __launch_bounds__(256) void gemm128(const void* __restrict__ Av,
                                               const u16* __restrict__ BT,
                                               void* __restrict__ Cv,
                                               const float* __restrict__ bias,
                                               const float* __restrict__ resid,
                                               int M, int N, int K, int relu,
                                               u16* __restrict__ Cbf) {
  __shared__ u16 As[128 * 32];
  __shared__ u16 Bs[128 * 32];
  const int tid = threadIdx.x;
  const int wave = tid >> 6, lane = tid & 63;
  const int m0 = blockIdx.y * 128, n0 = blockIdx.x * 128;
  const int wm = wave >> 1, wn = wave & 1;
  const int fr = lane & 15, quad = lane >> 4;

  f32x4 acc[4][4] = {};

  const int srow = wave * 32 + (lane >> 2);
  const int skcol = (lane & 3) * 8;

  for (int k0 = 0; k0 < K; k0 += 32) {
    __syncthreads();
    if (AF32) {
      const float* Ap = (const float*)Av + (long)(m0 + (tid >> 1)) * K + k0 + (tid & 1) * 16;
      f32x4 f0 = *(const f32x4*)Ap, f1 = *(const f32x4*)(Ap + 4);
      f32x4 f2 = *(const f32x4*)(Ap + 8), f3 = *(const f32x4*)(Ap + 12);
      u16x8 p0, p1;
#pragma unroll
      for (int j = 0; j < 4; j++) {
        p0[j] = f2bf(f0[j]); p0[j + 4] = f2bf(f1[j]);
        p1[j] = f2bf(f2[j]); p1[j + 4] = f2bf(f3[j]);
      }
      *(u16x8*)&As[(tid >> 1) * 32 + (tid & 1) * 16] = p0;
      *(u16x8*)&As[(tid >> 1) * 32 + (tid & 1) * 16 + 8] = p1;
    } else {
      const u16* Ag = (const u16*)Av + (long)(m0 + srow) * K + k0 + skcol;
      gl2lds16(Ag, &As[(wave * 32) * 32]);
      gl2lds16(Ag + 16 * (long)K, &As[(wave * 32 + 16) * 32]);
    }
    {
      const u16* Bg = BT + (long)(n0 + srow) * K + k0 + skcol;
      gl2lds16(Bg, &Bs[(wave * 32) * 32]);
      gl2lds16(Bg + 16 * (long)K, &Bs[(wave * 32 + 16) * 32]);
    }
    __syncthreads();

    bf16x8 af[4], bfr[4];
#pragma unroll
    for (int mi = 0; mi < 4; mi++)
      af[mi] = __builtin_bit_cast(bf16x8, *(const u16x8*)&As[(wm * 64 + mi * 16 + fr) * 32 + quad * 8]);
#pragma unroll
    for (int ni = 0; ni < 4; ni++)
      bfr[ni] = __builtin_bit_cast(bf16x8, *(const u16x8*)&Bs[(wn * 64 + ni * 16 + fr) * 32 + quad * 8]);
#pragma unroll
    for (int mi = 0; mi < 4; mi++)
#pragma unroll
      for (int ni = 0; ni < 4; ni++)
        acc[mi][ni] = __builtin_amdgcn_mfma_f32_16x16x32_bf16(af[mi], bfr[ni], acc[mi][ni], 0, 0, 0);
  }

#pragma unroll
  for (int mi = 0; mi < 4; mi++)
#pragma unroll
    for (int ni = 0; ni < 4; ni++)
#pragma unroll
      for (int r = 0; r < 4; r++) {
        int gm = m0 + wm * 64 + mi * 16 + quad * 4 + r;
        int gn = n0 + wn * 64 + ni * 16 + fr;
        float v = acc[mi][ni][r];
        if (bias) v += bias[gn];
        if (resid) v += resid[(long)gm * N + gn];
        if (relu) v = fmaxf(v, 0.f);
        if (CF32) ((float*)Cv)[(long)gm * N + gn] = v;
        else      ((u16*)Cv)[(long)gm * N + gn] = f2bf(v);
        if (Cbf) Cbf[(long)gm * N + gn] = f2bf(v);
      }
}

// ------------- MFMA causal flash attention, paired q-tiles, pre-transposed V -------------
__global__ __launch_bounds__(256) void attn_mfma3(const u16* __restrict__ QKV,
                                                  const u16* __restrict__ VTg,
                                                  u16* __restrict__ attn) {
  int p = blockIdx.x, h = blockIdx.y, b = blockIdx.z;
  int tid = threadIdx.x;
  int wq = tid >> 6, lane = tid & 63;
  int fr = lane & 15, quad = lane >> 4;
  int kf = quad * 8;

  __shared__ u16 Qs[64][72];
  __shared__ u16 Ks[64][72];
  __shared__ u16 Vt[64][72];
  __shared__ u16 Ps[4][16][72];

  const u16* base = QKV + (long)b * S_ * 3072;
  const u16* vbase = VTg + (long)(b * 16 + h) * 64 * S_;
  int st = tid >> 2;
  int sd = (tid & 3) * 16;

  for (int ti = 0; ti < 2; ti++) {
    int qt = ti ? (31 - p) : p;

    {  // stage Q scaled by 1/32 (= E^-0.5)
      const u16* qr = base + (long)(qt * 64 + st) * 3072 + h * 64 + sd;
      u16x8 a = *(const u16x8*)qr, d = *(const u16x8*)(qr + 8);
      u16x8 oa, od;
#pragma unroll
      for (int j = 0; j < 8; j++) {
        oa[j] = f2bf(bf2f(a[j]) * 0.03125f);
        od[j] = f2bf(bf2f(d[j]) * 0.03125f);
      }
      *(u16x8*)&Qs[st][sd] = oa;
      *(u16x8*)&Qs[st][sd + 8] = od;
    }
    __syncthreads();
    bf16x8 qf0 = __builtin_bit_cast(bf16x8, *(const u16x8*)&Qs[wq * 16 + fr][kf]);
    bf16x8 qf1 = __builtin_bit_cast(bf16x8, *(const u16x8*)&Qs[wq * 16 + fr][32 + kf]);

    f32x4 acc[4] = {};
    float m[4], l[4];
#pragma unroll
    for (int r = 0; r < 4; r++) { m[r] = -INFINITY; l[r] = 0.f; }

    for (int c = 0; c <= qt; c++) {
      int t0 = c * 64;
      __syncthreads();
      {  // K rows (vector), V from pre-transposed VTg (vector)
        const u16* kr = base + (long)(t0 + st) * 3072 + 1024 + h * 64 + sd;
        u16x8 k0 = *(const u16x8*)kr, k1 = *(const u16x8*)(kr + 8);
        const u16* vr = vbase + (long)st * S_ + t0 + sd;  // st=d, sd=t-offset
        u16x8 v0 = *(const u16x8*)vr, v1 = *(const u16x8*)(vr + 8);
        *(u16x8*)&Ks[st][sd] = k0;
        *(u16x8*)&Ks[st][sd + 8] = k1;
        *(u16x8*)&Vt[st][sd] = v0;
        *(u16x8*)&Vt[st][sd + 8] = v1;
      }
      __syncthreads();

      f32x4 sc[4] = {};
#pragma unroll
      for (int nt = 0; nt < 4; nt++) {
        bf16x8 b0 = __builtin_bit_cast(bf16x8, *(const u16x8*)&Ks[nt * 16 + fr][kf]);
        bf16x8 b1 = __builtin_bit_cast(bf16x8, *(const u16x8*)&Ks[nt * 16 + fr][32 + kf]);
        sc[nt] = __builtin_amdgcn_mfma_f32_16x16x32_bf16(qf0, b0, sc[nt], 0, 0, 0);
        sc[nt] = __builtin_amdgcn_mfma_f32_16x16x32_bf16(qf1, b1, sc[nt], 0, 0, 0);
      }

      if (c == qt) {  // diagonal chunk mask
        int qloc = wq * 16 + quad * 4;
#pragma unroll
        for (int nt = 0; nt < 4; nt++)
#pragma unroll
          for (int r = 0; r < 4; r++)
            if (nt * 16 + fr > qloc + r) sc[nt][r] = -1e30f;
      }

      float al[4], ps[4];
#pragma unroll
      for (int r = 0; r < 4; r++) {
        float v = fmaxf(fmaxf(sc[0][r], sc[1][r]), fmaxf(sc[2][r], sc[3][r]));
#pragma unroll
        for (int off = 1; off < 16; off <<= 1) v = fmaxf(v, __shfl_xor(v, off));
        float mn = fmaxf(m[r], v);
        al[r] = __expf(m[r] - mn);
        m[r] = mn;
        ps[r] = 0.f;
      }
#pragma unroll
      for (int nt = 0; nt < 4; nt++)
#pragma unroll
        for (int r = 0; r < 4; r++) {
          float pv = __expf(sc[nt][r] - m[r]);
          sc[nt][r] = pv;
          ps[r] += pv;
        }
#pragma unroll
      for (int r = 0; r < 4; r++) {
#pragma unroll
        for (int off = 1; off < 16; off <<= 1) ps[r] += __shfl_xor(ps[r], off);
        l[r] = l[r] * al[r] + ps[r];
#pragma unroll
        for (int nt = 0; nt < 4; nt++) acc[nt][r] *= al[r];
      }

      // P: C-layout -> per-wave LDS -> A-layout (wave-private; lgkmcnt orders)
#pragma unroll
      for (int nt = 0; nt < 4; nt++)
#pragma unroll
        for (int r = 0; r < 4; r++)
          Ps[wq][quad * 4 + r][nt * 16 + fr] = f2bf(sc[nt][r]);

      bf16x8 pa0 = __builtin_bit_cast(bf16x8, *(const u16x8*)&Ps[wq][fr][kf]);
      bf16x8 pa1 = __builtin_bit_cast(bf16x8, *(const u16x8*)&Ps[wq][fr][32 + kf]);
#pragma unroll
      for (int nt = 0; nt < 4; nt++) {
        bf16x8 vb0 = __builtin_bit_cast(bf16x8, *(const u16x8*)&Vt[nt * 16 + fr][kf]);
        bf16x8 vb1 = __builtin_bit_cast(bf16x8, *(const u16x8*)&Vt[nt * 16 + fr][32 + kf]);
        acc[nt] = __builtin_amdgcn_mfma_f32_16x16x32_bf16(pa0, vb0, acc[nt], 0, 0, 0);
        acc[nt] = __builtin_amdgcn_mfma_f32_16x16x32_bf16(pa1, vb1, acc[nt], 0, 0, 0);
      }
    }

    long row = (long)b * S_ + qt * 64 + wq * 16 + quad * 4;
#pragma unroll
    for (int nt = 0; nt < 4; nt++)
#pragma unroll
      for (int r = 0; r < 4; r++)
        attn[(row + r) * 1024 + h * 64 + nt * 16 + fr] = f2bf(acc[nt][r] / l[r]);
  }
}

extern "C" void kernel_launch(void* const* d_in, const int* in_sizes, int n_in,
                              void* d_out, int out_size, void* d_ws, size_t ws_size,
                              hipStream_t stream) {
  (void)in_sizes; (void)n_in; (void)out_size;
  const float* x  = (const float*)d_in[0];
  const float* Wq = (const float*)d_in[1];
  const float* Wk = (const float*)d_in[2];
  const float* Wv = (const float*)d_in[3];
  const float* Wo = (const float*)d_in[4];
  const float* bo = (const float*)d_in[5];
  const float* W1 = (const float*)d_in[6];
  const float* b1 = (const float*)d_in[7];
  const float* W2 = (const float*)d_in[8];
  const float* b2 = (const float*)d_in[9];
  float* out = (float*)d_out;  // fp32 output

  char* ws = (char*)d_ws;
  u16*   QKV  = (u16*)(ws);                  // [0, 48MiB)
  u16*   attn = (u16*)(ws + 50331648);       // [48MiB, 64MiB)
  u16*   hbuf = (u16*)(ws);                  // [0, 64MiB)
  float* x1   = (float*)(ws + 67108864);     // [64MiB, 96MiB) fp32
  u16*   VTg  = (u16*)(ws + 67108864);       // [64MiB, 80MiB) bf16 (dead before x1 written)
  u16*   xb   = (u16*)(ws + 83886080);       // [80MiB, 96MiB) bf16 (dead before x1 written)
  u16*   WT   = (u16*)(ws + 100663296);      // 6MiB
  u16*   WoT  = (u16*)(ws + 106954752);      // 2MiB
  u16*   W1T  = (u16*)(ws + 109051904);      // 8MiB
  u16*   W2T  = (u16*)(ws + 117440512);      // 8MiB -> ends 120MiB
  u16*   x1b  = (u16*)(ws + 125829120);      // [120MiB, 136MiB) if ws allows
  bool bigws = ws_size >= (size_t)142606336; // 136 MiB

  cast_bf16_k<<<4096, 256, 0, stream>>>(x, xb, (long)8192 * 1024);
  castT_k<<<dim3(2, 32, 16), 256, 0, stream>>>(Wq, WT, 1024, 64);
  castT_k<<<dim3(2, 32, 16), 256, 0, stream>>>(Wk, WT + 1048576, 1024, 64);
  castT_k<<<dim3(2, 32, 16), 256, 0, stream>>>(Wv, WT + 2097152, 1024, 64);
  castT_k<<<dim3(32, 32, 1), 256, 0, stream>>>(Wo, WoT, 1024, 1024);
  castT_k<<<dim3(128, 32, 1), 256, 0, stream>>>(W1, W1T, 1024, 4096);
  castT_k<<<dim3(32, 128, 1), 256, 0, stream>>>(W2, W2T, 4096, 1024);

  // QKV = xb @ [Wq|Wk|Wv]   [8192,3072] bf16
  gemm128<false, false><<<dim3(24, 64), 256, 0, stream>>>(xb, WT, QKV, nullptr, nullptr, 8192, 3072, 1024, 0, nullptr);
  // V transpose -> VTg[b,h][d][t]
  vT_k<<<dim3(64, 2, 64), 256, 0, stream>>>(QKV, VTg);
  // causal attention -> attn [8192,1024] bf16
  attn_mfma3<<<dim3(16, H_, B_), 256, 0, stream>>>(QKV, VTg, attn);
  // x1 = x + attn @ Wo + bo   (fp32, + optional bf16 dual-store)
  gemm128<false, true><<<dim3(8, 64), 256, 0, stream>>>(attn, WoT, x1, bo, x, 8192, 1024, 1024, 0, bigws ? x1b : nullptr);
  // h = relu(x1 @ W1 + b1)   [8192,4096] bf16
  if (bigws)
    gemm128<false, false><<<dim3(32, 64), 256, 0, stream>>>(x1b, W1T, hbuf, b1, nullptr, 8192, 4096, 1024, 1, nullptr);
  else
    gemm128<true, false><<<dim3(32, 64), 256, 0, stream>>>(x1, W1T, hbuf, b1, nullptr, 8192, 4096, 1024, 1, nullptr);
  // out = x1 + h @ W2 + b2   (fp32 -> d_out)
  gemm128<false, true><<<dim3(8, 64), 256, 0, stream>>>(hbuf, W2T, out, b2, x1, 8192, 1024, 4096, 0, nullptr);
}